// Round 4
// baseline (468.414 us; speedup 1.0000x reference)
//
#include <hip/hip_runtime.h>

#define TAGS 64
#define MAXT 512
#define NEG  -10000.0f
#define CH   8   // feat-staging chunk: steps per LDS buffer

// Two waves (128 threads) per batch; lane = "next" tag in both waves.
// Wave w computes the partial max over prev in [32w, 32w+32) -> half the
// per-wave VALU work and 2 waves/SIMD chip-wide (2048 waves / 1024 SIMDs),
// so one wave's LDS-latency stalls overlap the other's issue (round-3
// profile: 1382 cyc/step vs ~506 issue => ~60% exposed-stall at 1 wave/SIMD).
// Wave 1 ships (val,idx) via one ds_write_b64; wave 0 combines (strict '>'
// keeps wave-0 = lower prev indices on ties = numpy first-occurrence),
// adds emission, writes fv + bptr. Two s_barriers per step.
__global__ __launch_bounds__(128, 1) void crf_viterbi(
    const float* __restrict__ feats,   // [B, T, K]
    const float* __restrict__ weights, // [K, K] (weights[next][prev])
    const int*   __restrict__ lens,    // [B]
    float*       __restrict__ out,     // [B] scores ++ [B*T] paths (as f32)
    int B, int T)
{
    const int b    = blockIdx.x;
    const int tid  = threadIdx.x;
    const int lane = tid & 63;                 // next tag
    const int wv   = tid >> 6;                 // 0 or 1 (wave-uniform)
    const int len  = lens[b];                  // 1..T

    __shared__ float  fv[TAGS];
    __shared__ float2 part[TAGS];              // wave-1 partial (val, idx bits)
    __shared__ float  fbuf[2][CH * TAGS];      // 2 x 2 KB feat staging (wave 0)
    __shared__ unsigned char  bptr[MAXT * TAGS];
    __shared__ unsigned short path[MAXT];
    __shared__ int s_best;
    // ~38.7 KB -> 4 blocks/CU

    // half W row for this lane: prevs [32*wv, 32*wv+32) -> 32 VGPRs
    float w[32];
    #pragma unroll
    for (int i = 0; i < 8; ++i) {
        const float4 v = *reinterpret_cast<const float4*>(
            weights + lane * TAGS + wv * 32 + i * 4);
        w[4*i+0] = v.x; w[4*i+1] = v.y; w[4*i+2] = v.z; w[4*i+3] = v.w;
    }
    const float wEnd = weights[1 * TAGS + lane];  // wave 0 only

    if (wv == 0) fv[lane] = (lane == 0) ? 0.0f : NEG;   // START = 0

    const float* fb  = feats + (size_t)b * T * TAGS;
    const int    lim = len * TAGS - 4;            // clamp for tail loads

    // prologue: wave 0 stages chunk 0, issues chunk-1 loads
    float4 n0, n1;
    if (wv == 0) {
        int o0 = 4 * lane;        if (o0 > lim) o0 = lim;
        int o1 = 256 + 4 * lane;  if (o1 > lim) o1 = lim;
        *reinterpret_cast<float4*>(&fbuf[0][4 * lane])       = *reinterpret_cast<const float4*>(fb + o0);
        *reinterpret_cast<float4*>(&fbuf[0][256 + 4 * lane]) = *reinterpret_cast<const float4*>(fb + o1);
        int p0 = CH * TAGS + 4 * lane;        if (p0 > lim) p0 = lim;
        int p1 = CH * TAGS + 256 + 4 * lane;  if (p1 > lim) p1 = lim;
        n0 = *reinterpret_cast<const float4*>(fb + p0);
        n1 = *reinterpret_cast<const float4*>(fb + p1);
    }
    __syncthreads();                              // fv init visible

    float nf = NEG;                               // wave 0: true fv[lane]

    auto step = [&](int cbuf, int i, int t) {
        // partial add+argmax over this wave's 32 prevs; ascending pairing +
        // strict '>' == numpy first-occurrence argmax, exact f32
        float gv[8]; int gi[8];
        #pragma unroll
        for (int g = 0; g < 8; ++g) {
            const float4 fq = *reinterpret_cast<const float4*>(&fv[wv * 32 + g * 4]);
            const int base = wv * 32 + g * 4;
            const float c0 = fq.x + w[4*g+0];
            const float c1 = fq.y + w[4*g+1];
            const float c2 = fq.z + w[4*g+2];
            const float c3 = fq.w + w[4*g+3];
            const bool g01 = c1 > c0;
            const float v01 = g01 ? c1 : c0; const int i01 = base + (g01 ? 1 : 0);
            const bool g23 = c3 > c2;
            const float v23 = g23 ? c3 : c2; const int i23 = base + (g23 ? 3 : 2);
            const bool gg = v23 > v01;
            gv[g] = gg ? v23 : v01; gi[g] = gg ? i23 : i01;
        }
        #pragma unroll
        for (int n = 4; n >= 1; n >>= 1) {
            #pragma unroll
            for (int k = 0; k < n; ++k) {
                const bool g = gv[2*k+1] > gv[2*k];
                gv[k] = g ? gv[2*k+1] : gv[2*k];
                gi[k] = g ? gi[2*k+1] : gi[2*k];
            }
        }
        float feat = 0.0f;
        if (wv == 1) {
            float2 p; p.x = gv[0]; p.y = __int_as_float(gi[0]);
            part[lane] = p;                       // one ds_write_b64
        } else {
            feat = fbuf[cbuf][i * TAGS + lane];   // overlap with wave-1 write
        }
        __syncthreads();                          // partial visible
        if (wv == 0) {
            const float2 p = part[lane];          // one ds_read_b64
            const bool g = p.x > gv[0];           // ties -> wave 0 (lower idx)
            const float val = g ? p.x : gv[0];
            const int   idx = g ? __float_as_int(p.y) : gi[0];
            nf = val + feat;                      // emission added after max
            fv[lane] = nf;
            bptr[t * TAGS + lane] = (unsigned char)idx;
        }
        __syncthreads();                          // fv visible to both waves
    };

    const int nfull = len / CH;
    for (int c = 0; c < nfull; ++c) {
        #pragma unroll
        for (int i = 0; i < CH; ++i) step(c & 1, i, c * CH + i);
        if (wv == 0) {                            // stage c+1, issue c+2 loads
            *reinterpret_cast<float4*>(&fbuf[(c + 1) & 1][4 * lane])       = n0;
            *reinterpret_cast<float4*>(&fbuf[(c + 1) & 1][256 + 4 * lane]) = n1;
            int o0 = (c + 2) * CH * TAGS + 4 * lane;        if (o0 > lim) o0 = lim;
            int o1 = (c + 2) * CH * TAGS + 256 + 4 * lane;  if (o1 > lim) o1 = lim;
            n0 = *reinterpret_cast<const float4*>(fb + o0);
            n1 = *reinterpret_cast<const float4*>(fb + o1);
        }
    }
    const int rem = len - nfull * CH;             // 0..7 remainder steps
    for (int i = 0; i < rem; ++i) step(nfull & 1, i, nfull * CH + i);

    // terminal = fv + W[END][prev]; wave 0 holds true fv in nf
    if (wv == 0) {
        float tv = nf + wEnd;
        int   ti = lane;
        #pragma unroll
        for (int off = 32; off >= 1; off >>= 1) {
            const float ov = __shfl_xor(tv, off);
            const int   oi = __shfl_xor(ti, off);
            if (ov > tv || (ov == tv && oi < ti)) { tv = ov; ti = oi; }
        }
        if (lane == 0) { out[b] = tv; s_best = ti; }
    }
    __syncthreads();
    const int bestlast = s_best;

    // padding region: path[t] = bestlast for t in [len-1, T)
    for (int t = tid; t < T; t += 128)
        if (t >= len - 1) path[t] = (unsigned short)bestlast;

    // serial chase (tid 0; bptr written by wave 0 = same wave, in order)
    if (tid == 0) {
        int tag = bestlast;
        for (int t = len - 1; t >= 1; --t) {
            tag = bptr[t * TAGS + tag];
            path[t - 1] = (unsigned short)tag;
        }
    }
    __syncthreads();

    // coalesced path writeback (tags as float32)
    float* pout = out + B + (size_t)b * T;
    for (int t = tid; t < T; t += 128)
        pout[t] = (float)path[t];
}

extern "C" void kernel_launch(void* const* d_in, const int* in_sizes, int n_in,
                              void* d_out, int out_size, void* d_ws, size_t ws_size,
                              hipStream_t stream) {
    const float* feats   = (const float*)d_in[0];
    const float* weights = (const float*)d_in[1];
    const int*   lens    = (const int*)d_in[2];
    float*       out     = (float*)d_out;

    const int B = in_sizes[2];
    const int T = in_sizes[0] / (B * TAGS);

    crf_viterbi<<<dim3(B), dim3(128), 0, stream>>>(feats, weights, lens, out, B, T);
}

// Round 5
// 425.498 us; speedup vs baseline: 1.1009x; 1.1009x over previous
//
#include <hip/hip_runtime.h>

#define TAGS 64
#define MAXT 512
#define NEG  -10000.0f
#define CH   8   // feat-staging chunk: steps per LDS buffer

// One wave (64 lanes) per batch. lane = "next" tag. Single-wave block, no
// barriers (same-wave LDS ops are program-ordered). feats staged via LDS
// double buffer one chunk ahead (round 3: removed global-latency stalls).
//
// Round-5 restructure: the fv->fv recurrence critical path carries ONLY the
// value max (adds -> v_max3 tree -> +feat -> ds_write). The backpointer
// index (argmax) is computed by a DEFERRED equality scan (cmp/cndmask +
// v_min3_u32 tree) that is off the critical path — its issue slots fill the
// next step's LDS-read latency. Round-3 profile: 1382 cyc/step vs ~506
// issue; the joint value+index tree kept ~190 index ops on the chain.
__global__ __launch_bounds__(64, 1) void crf_viterbi(
    const float* __restrict__ feats,   // [B, T, K]
    const float* __restrict__ weights, // [K, K] (weights[next][prev])
    const int*   __restrict__ lens,    // [B]
    float*       __restrict__ out,     // [B] scores ++ [B*T] paths (as f32)
    int B, int T)
{
    const int b    = blockIdx.x;
    const int lane = threadIdx.x;              // next tag
    const int len  = lens[b];                  // 1..T

    __shared__ float fv[TAGS];
    __shared__ float fbuf[2][CH * TAGS];       // 2 x 2 KB feat staging
    __shared__ unsigned char  bptr[MAXT * TAGS];
    __shared__ unsigned short path[MAXT];
    // ~38.1 KB LDS

    // W row for this lane (as float4 quads -> packed adds)
    float4 w4[16];
    #pragma unroll
    for (int i = 0; i < 16; ++i)
        w4[i] = *reinterpret_cast<const float4*>(weights + lane * TAGS + i * 4);
    const float wEnd = weights[1 * TAGS + lane];  // transition into END

    fv[lane] = (lane == 0) ? 0.0f : NEG;          // START = 0

    const float* fb  = feats + (size_t)b * T * TAGS;
    const int    lim = len * TAGS - 4;            // clamp for tail loads

    float nf = NEG;                               // this lane's running fv

#define F3(a, b, c) fmaxf(fmaxf((a), (b)), (c))
#define M3(a, b, c) min(min((a), (b)), (c))

    auto step = [&](int cbuf, int i, int t) {
        const float feat = fbuf[cbuf][i * TAGS + lane];  // early, off-chain
        // gather fv quads (16x ds_read_b128, back-to-back issue)
        float4 fq[16];
        #pragma unroll
        for (int g = 0; g < 16; ++g)
            fq[g] = *reinterpret_cast<const float4*>(&fv[g * 4]);
        // c = fv + w  (float4 adds -> v_pk_add_f32 pairs)
        float4 c4[16];
        #pragma unroll
        for (int g = 0; g < 16; ++g) {
            c4[g].x = fq[g].x + w4[g].x;
            c4[g].y = fq[g].y + w4[g].y;
            c4[g].z = fq[g].z + w4[g].z;
            c4[g].w = fq[g].w + w4[g].w;
        }
        const float* c = reinterpret_cast<const float*>(c4);

        // ---- value-only max: 3-ary tree (v_max3_f32), depth 4 ----
        float v1[22];
        #pragma unroll
        for (int k = 0; k < 21; ++k) v1[k] = F3(c[3*k], c[3*k+1], c[3*k+2]);
        v1[21] = c[63];
        float v2[8];
        #pragma unroll
        for (int k = 0; k < 7; ++k) v2[k] = F3(v1[3*k], v1[3*k+1], v1[3*k+2]);
        v2[7] = v1[21];
        const float v30 = F3(v2[0], v2[1], v2[2]);
        const float v31 = F3(v2[3], v2[4], v2[5]);
        const float v32 = fmaxf(v2[6], v2[7]);
        const float m   = F3(v30, v31, v32);

        nf = m + feat;                 // emission added after max
        fv[lane] = nf;                 // *** unblocks step t+1 ***

        // ---- deferred index: first p with c[p]==m (numpy first-occurrence,
        // exact f32 ==; no NaNs; -0.0==+0.0 consistent with ref) ----
        unsigned e[64];
        #pragma unroll
        for (int p = 0; p < 64; ++p) e[p] = (c[p] == m) ? (unsigned)p : 64u;
        unsigned u1[22];
        #pragma unroll
        for (int k = 0; k < 21; ++k) u1[k] = M3(e[3*k], e[3*k+1], e[3*k+2]);
        u1[21] = e[63];
        unsigned u2[8];
        #pragma unroll
        for (int k = 0; k < 7; ++k) u2[k] = M3(u1[3*k], u1[3*k+1], u1[3*k+2]);
        u2[7] = u1[21];
        const unsigned u30 = M3(u2[0], u2[1], u2[2]);
        const unsigned u31 = M3(u2[3], u2[4], u2[5]);
        const unsigned u32 = min(u2[6], u2[7]);
        const unsigned idx = M3(u30, u31, u32);

        bptr[t * TAGS + lane] = (unsigned char)idx;
    };

    // prologue: stage chunk 0 -> fbuf[0]; issue chunk-1 loads
    {
        int o0 = 4 * lane;        if (o0 > lim) o0 = lim;
        int o1 = 256 + 4 * lane;  if (o1 > lim) o1 = lim;
        *reinterpret_cast<float4*>(&fbuf[0][4 * lane])       = *reinterpret_cast<const float4*>(fb + o0);
        *reinterpret_cast<float4*>(&fbuf[0][256 + 4 * lane]) = *reinterpret_cast<const float4*>(fb + o1);
    }
    float4 n0, n1;
    {
        int o0 = CH * TAGS + 4 * lane;        if (o0 > lim) o0 = lim;
        int o1 = CH * TAGS + 256 + 4 * lane;  if (o1 > lim) o1 = lim;
        n0 = *reinterpret_cast<const float4*>(fb + o0);
        n1 = *reinterpret_cast<const float4*>(fb + o1);
    }

    int cb = 0;
    const int nfull = len / CH;
    for (int c = 0; c < nfull; ++c) {
        #pragma unroll
        for (int i = 0; i < CH; ++i) step(cb, i, c * CH + i);
        // stage chunk c+1 (loads landed ~8 steps ago), issue chunk c+2
        *reinterpret_cast<float4*>(&fbuf[cb ^ 1][4 * lane])       = n0;
        *reinterpret_cast<float4*>(&fbuf[cb ^ 1][256 + 4 * lane]) = n1;
        {
            int o0 = (c + 2) * CH * TAGS + 4 * lane;        if (o0 > lim) o0 = lim;
            int o1 = (c + 2) * CH * TAGS + 256 + 4 * lane;  if (o1 > lim) o1 = lim;
            n0 = *reinterpret_cast<const float4*>(fb + o0);
            n1 = *reinterpret_cast<const float4*>(fb + o1);
        }
        cb ^= 1;
    }
    const int rem = len - nfull * CH;             // 0..7 remainder steps
    for (int i = 0; i < rem; ++i) step(cb, i, nfull * CH + i);

    // terminal = fv + W[END][prev]; first-max argmax via shuffle butterfly
    float tv = nf + wEnd;
    int   ti = lane;
    #pragma unroll
    for (int off = 32; off >= 1; off >>= 1) {
        const float ov = __shfl_xor(tv, off);
        const int   oi = __shfl_xor(ti, off);
        if (ov > tv || (ov == tv && oi < ti)) { tv = ov; ti = oi; }
    }
    if (lane == 0) out[b] = tv;
    const int bestlast = ti;                      // uniform across lanes

    // padding region: path[t] = bestlast for t in [len-1, T)
    for (int t = lane; t < T; t += 64)
        if (t >= len - 1) path[t] = (unsigned short)bestlast;
    __builtin_amdgcn_wave_barrier();

    // serial chase (lane 0, LDS-resident backpointers)
    if (lane == 0) {
        int tag = bestlast;
        for (int t = len - 1; t >= 1; --t) {
            tag = bptr[t * TAGS + tag];
            path[t - 1] = (unsigned short)tag;
        }
    }
    __builtin_amdgcn_wave_barrier();

    // coalesced path writeback (tags as float32)
    float* pout = out + B + (size_t)b * T;
    for (int t = lane; t < T; t += 64)
        pout[t] = (float)path[t];
}

extern "C" void kernel_launch(void* const* d_in, const int* in_sizes, int n_in,
                              void* d_out, int out_size, void* d_ws, size_t ws_size,
                              hipStream_t stream) {
    const float* feats   = (const float*)d_in[0];
    const float* weights = (const float*)d_in[1];
    const int*   lens    = (const int*)d_in[2];
    float*       out     = (float*)d_out;

    const int B = in_sizes[2];
    const int T = in_sizes[0] / (B * TAGS);

    crf_viterbi<<<dim3(B), dim3(64), 0, stream>>>(feats, weights, lens, out, B, T);
}